// Round 2
// baseline (374.512 us; speedup 1.0000x reference)
//
#include <hip/hip_runtime.h>
#include <hip/hip_bf16.h>

typedef __attribute__((ext_vector_type(8))) short bf16x8;
typedef __attribute__((ext_vector_type(4))) float f32x4;

#define AS1 __attribute__((address_space(1)))
#define AS3 __attribute__((address_space(3)))

__device__ __forceinline__ unsigned short f2bf(float f) {
  unsigned u = __float_as_uint(f);
  u += 0x7fff + ((u >> 16) & 1);   // RNE
  return (unsigned short)(u >> 16);
}

__device__ __forceinline__ void gload_lds16(const void* g, void* l) {
  __builtin_amdgcn_global_load_lds((const AS1 unsigned int*)g,
                                   (AS3 unsigned int*)l, 16, 0, 0);
}

// ---------------------------------------------------------------------------
// C[M,N] = scale * (A[M,K] @ Bt[N,K]^T) + bias.  A,Bt bf16 row-major,
// C fp32 or bf16(ushort). Tile 128 x (NJ*32), BK=32, 256 thr = 4 waves (2x2),
// each wave 4 x NJ of 16x16x32 MFMA. global_load_lds width-16 staging (m97)
// with XOR chunk swizzle: LDS chunk p of row r holds global chunk
// p ^ (r&3) ^ ((r>>2)&3)  -> 8-way bank conflicts become 2-way (free).
// ---------------------------------------------------------------------------
template <typename OutT, bool BIAS, int NJ>
__global__ __launch_bounds__(256) void gemm_bt(
    const unsigned short* __restrict__ A,
    const unsigned short* __restrict__ Bt,
    OutT* __restrict__ C,
    const float* __restrict__ bias,
    int Kd, int lda, int ldb, int ldc,
    long sA, long sB, long sC,
    float scale) {
  constexpr int TN = NJ * 32;
  __shared__ unsigned short ldsA[128 * 32];
  __shared__ unsigned short ldsB[TN * 32];
  const int bz = blockIdx.z;
  A  += (size_t)bz * sA + (size_t)blockIdx.x * 128 * lda;
  Bt += (size_t)bz * sB + (size_t)blockIdx.y * TN * ldb;

  const int tid  = threadIdx.x;
  const int wave = tid >> 6;
  const int lane = tid & 63;
  const int wm   = (wave >> 1) * 64;        // wave row offset
  const int wn   = (wave & 1) * (NJ * 16);  // wave col offset
  const int quad = lane >> 4;
  const int l16  = lane & 15;
  const int srow = wave * 16 + (lane >> 2);  // staging row
  // global chunk this lane fetches (stage-side swizzle)
  const int cg   = ((lane & 3) ^ ((lane >> 2) & 3) ^ (lane >> 4)) * 8;
  // LDS chunk to read for k-chunk `quad` (read-side inverse swizzle)
  const int prd  = (quad ^ (l16 & 3) ^ ((l16 >> 2) & 3)) * 8;

  f32x4 acc[4][NJ] = {};

  for (int k0 = 0; k0 < Kd; k0 += 32) {
    __syncthreads();
    gload_lds16(A + (size_t)srow * lda + k0 + cg,        (char*)ldsA + wave * 1024);
    gload_lds16(A + (size_t)(srow + 64) * lda + k0 + cg, (char*)ldsA + 4096 + wave * 1024);
#pragma unroll
    for (int n = 0; n < TN; n += 64)
      gload_lds16(Bt + (size_t)(srow + n) * ldb + k0 + cg, (char*)ldsB + n * 64 + wave * 1024);
    __syncthreads();

    bf16x8 af[4], bfr[NJ];
#pragma unroll
    for (int i = 0; i < 4; ++i)
      af[i] = *(const bf16x8*)&ldsA[(wm + i * 16 + l16) * 32 + prd];
#pragma unroll
    for (int j = 0; j < NJ; ++j)
      bfr[j] = *(const bf16x8*)&ldsB[(wn + j * 16 + l16) * 32 + prd];
#pragma unroll
    for (int i = 0; i < 4; ++i)
#pragma unroll
      for (int j = 0; j < NJ; ++j)
        acc[i][j] = __builtin_amdgcn_mfma_f32_16x16x32_bf16(af[i], bfr[j], acc[i][j], 0, 0, 0);
  }

  const int row0 = blockIdx.x * 128 + wm;
  const int col0 = blockIdx.y * TN + wn;
  C += (size_t)bz * sC;
#pragma unroll
  for (int i = 0; i < 4; ++i) {
#pragma unroll
    for (int j = 0; j < NJ; ++j) {
      const int col = col0 + j * 16 + l16;
      const float bv = BIAS ? bias[col] : 0.0f;
#pragma unroll
      for (int r = 0; r < 4; ++r) {
        const int row = row0 + i * 16 + quad * 4 + r;
        const float v = acc[i][j][r] * scale + bv;
        if constexpr (sizeof(OutT) == 4)
          C[(size_t)row * ldc + col] = v;
        else
          C[(size_t)row * ldc + col] = (OutT)f2bf(v);
      }
    }
  }
}

// fp32 -> bf16 flat convert (4 elems/thread)
__global__ void cvt_x(const float* __restrict__ in, unsigned short* __restrict__ out, int n4) {
  const int i = blockIdx.x * blockDim.x + threadIdx.x;
  if (i < n4) {
    const float4 v = ((const float4*)in)[i];
    uint2 o;
    o.x = (unsigned)f2bf(v.x) | ((unsigned)f2bf(v.y) << 16);
    o.y = (unsigned)f2bf(v.z) | ((unsigned)f2bf(v.w) << 16);
    ((uint2*)out)[i] = o;
  }
}

// fp32 [rows][cols] -> bf16 transposed [cols][rows]. block (64,4), 64x64 tiles.
__global__ void cvtT_w(const float* __restrict__ in, unsigned short* __restrict__ out,
                       int rows, int cols) {
  __shared__ unsigned short tile[64][65];
  const int r0 = blockIdx.y * 64, c0 = blockIdx.x * 64;
  for (int i = threadIdx.y; i < 64; i += 4)
    tile[i][threadIdx.x] = f2bf(in[(size_t)(r0 + i) * cols + c0 + threadIdx.x]);
  __syncthreads();
  for (int i = threadIdx.y; i < 64; i += 4)
    out[(size_t)(c0 + i) * rows + r0 + threadIdx.x] = tile[threadIdx.x][i];
}

// bf16 [b][rows][cols-slice] -> [b][cols][rows], strided input
__global__ void transpose_bf16(const unsigned short* __restrict__ in,
                               unsigned short* __restrict__ out,
                               int rows, int ld_in, long sIn,
                               int cols_out_rows /*=rows*/, long sOut) {
  __shared__ unsigned short tile[64][65];
  const int b = blockIdx.z;
  in  += (size_t)b * sIn;
  out += (size_t)b * sOut;
  const int r0 = blockIdx.y * 64, c0 = blockIdx.x * 64;
  for (int i = threadIdx.y; i < 64; i += 4)
    tile[i][threadIdx.x] = in[(size_t)(r0 + i) * ld_in + c0 + threadIdx.x];
  __syncthreads();
  for (int i = threadIdx.y; i < 64; i += 4)
    out[(size_t)(c0 + i) * cols_out_rows + r0 + threadIdx.x] = tile[threadIdx.x][i];
}

// One block per row of 2048 fp32 scores. Full row in registers (8/thread).
// Softmax in fp32, result written IN PLACE as bf16 (row stride 4096 elems).
__global__ __launch_bounds__(256) void softmax_inplace(float* __restrict__ scores) {
  float* p = scores + (size_t)blockIdx.x * 2048;
  const int t = threadIdx.x;
  float4 v0 = ((const float4*)p)[t * 2];
  float4 v1 = ((const float4*)p)[t * 2 + 1];

  float m = fmaxf(fmaxf(fmaxf(v0.x, v0.y), fmaxf(v0.z, v0.w)),
                  fmaxf(fmaxf(v1.x, v1.y), fmaxf(v1.z, v1.w)));
#pragma unroll
  for (int off = 32; off; off >>= 1) m = fmaxf(m, __shfl_xor(m, off, 64));

  __shared__ float red[4];
  __shared__ float bcast[2];
  const int wave = t >> 6, lane = t & 63;
  if (lane == 0) red[wave] = m;
  __syncthreads();
  if (t == 0) bcast[0] = fmaxf(fmaxf(red[0], red[1]), fmaxf(red[2], red[3]));
  __syncthreads();
  m = bcast[0];

  v0.x = __expf(v0.x - m); v0.y = __expf(v0.y - m);
  v0.z = __expf(v0.z - m); v0.w = __expf(v0.w - m);
  v1.x = __expf(v1.x - m); v1.y = __expf(v1.y - m);
  v1.z = __expf(v1.z - m); v1.w = __expf(v1.w - m);

  float s = v0.x + v0.y + v0.z + v0.w + v1.x + v1.y + v1.z + v1.w;
#pragma unroll
  for (int off = 32; off; off >>= 1) s += __shfl_xor(s, off, 64);
  if (lane == 0) red[wave] = s;
  __syncthreads();
  if (t == 0) bcast[1] = red[0] + red[1] + red[2] + red[3];
  __syncthreads();
  const float inv = 1.0f / bcast[1];

  uint4 ov;
  ov.x = (unsigned)f2bf(v0.x * inv) | ((unsigned)f2bf(v0.y * inv) << 16);
  ov.y = (unsigned)f2bf(v0.z * inv) | ((unsigned)f2bf(v0.w * inv) << 16);
  ov.z = (unsigned)f2bf(v1.x * inv) | ((unsigned)f2bf(v1.y * inv) << 16);
  ov.w = (unsigned)f2bf(v1.z * inv) | ((unsigned)f2bf(v1.w * inv) << 16);
  ((uint4*)p)[t] = ov;
}

// ---------------------------------------------------------------------------
extern "C" void kernel_launch(void* const* d_in, const int* in_sizes, int n_in,
                              void* d_out, int out_size, void* d_ws, size_t ws_size,
                              hipStream_t stream) {
  const float* x  = (const float*)d_in[0];
  const float* Wq = (const float*)d_in[1];
  const float* bq = (const float*)d_in[2];
  const float* Wk = (const float*)d_in[3];
  const float* bk = (const float*)d_in[4];
  const float* Wv = (const float*)d_in[5];
  const float* bv = (const float*)d_in[6];
  const float* Wo = (const float*)d_in[7];
  const float* bo = (const float*)d_in[8];
  float* out = (float*)d_out;

  char* ws = (char*)d_ws;
  size_t off = 0;
  auto alloc = [&](size_t bytes) { char* p = ws + off; off += (bytes + 255) & ~255UL; return p; };
  unsigned short* xb    = (unsigned short*)alloc(8192UL * 1024 * 2);   // 16 MiB
  unsigned short* Wqkvb = (unsigned short*)alloc(3072UL * 1024 * 2);   // 6 MiB [3072][1024] = WqT|WkT|WvT
  unsigned short* Wob   = (unsigned short*)alloc(1024UL * 1024 * 2);   // 2 MiB
  float*          bqkv  = (float*)alloc(3072UL * 4);
  unsigned short* qkv   = (unsigned short*)alloc(8192UL * 3072 * 2);   // 48 MiB [8192][3072]
  unsigned short* Vtb   = (unsigned short*)alloc(4UL * 1024 * 2048 * 2); // 16 MiB
  unsigned short* ctxb  = (unsigned short*)alloc(8192UL * 1024 * 2);   // 16 MiB
  float*          sc    = (float*)alloc(4UL * 2048 * 2048 * 4);        // 64 MiB

  const dim3 blk(256);

  // converts + weight transposes (QKV weights concatenated in Bt layout)
  cvt_x<<<2097152 / 256, 256, 0, stream>>>(x, xb, 2097152);
  cvtT_w<<<dim3(16, 16), dim3(64, 4), 0, stream>>>(Wq, Wqkvb, 1024, 1024);
  cvtT_w<<<dim3(16, 16), dim3(64, 4), 0, stream>>>(Wk, Wqkvb + 1024 * 1024, 1024, 1024);
  cvtT_w<<<dim3(16, 16), dim3(64, 4), 0, stream>>>(Wv, Wqkvb + 2048 * 1024, 1024, 1024);
  cvtT_w<<<dim3(16, 16), dim3(64, 4), 0, stream>>>(Wo, Wob, 1024, 1024);
  hipMemcpyAsync(bqkv,        bq, 1024 * 4, hipMemcpyDeviceToDevice, stream);
  hipMemcpyAsync(bqkv + 1024, bk, 1024 * 4, hipMemcpyDeviceToDevice, stream);
  hipMemcpyAsync(bqkv + 2048, bv, 1024 * 4, hipMemcpyDeviceToDevice, stream);

  // fused QKV projection: [8192,3072] = xb @ Wqkvb^T + bqkv
  gemm_bt<unsigned short, true, 4><<<dim3(64, 24, 1), blk, 0, stream>>>(
      xb, Wqkvb, qkv, bqkv, 1024, 1024, 1024, 3072, 0, 0, 0, 1.0f);

  // V^T per batch: [4][1024][2048]  (V = qkv cols 2048..3071)
  transpose_bf16<<<dim3(16, 32, 4), dim3(64, 4), 0, stream>>>(
      qkv + 2048, Vtb, 2048, 3072, 2048L * 3072, 2048, 1024L * 2048);

  // scores = (Q @ K^T) / 32, fp32, per batch
  gemm_bt<float, false, 4><<<dim3(16, 16, 4), blk, 0, stream>>>(
      qkv, qkv + 1024, sc, nullptr, 1024, 3072, 3072, 2048,
      2048L * 3072, 2048L * 3072, 2048L * 2048, 0.03125f);

  // softmax rows (in-place fp32 -> bf16, row stride 4096 bf16)
  softmax_inplace<<<8192, 256, 0, stream>>>(sc);

  // ctx = attn @ V  (attn bf16 lda=4096, Vt is Bt layout) — TN=64 tiles
  gemm_bt<unsigned short, false, 2><<<dim3(16, 16, 4), blk, 0, stream>>>(
      (unsigned short*)sc, Vtb, ctxb, nullptr, 2048, 4096, 2048, 1024,
      2048L * 4096, 1024L * 2048, 2048L * 1024, 1.0f);

  // out = ctx @ Wo + bo (fp32 out) — TN=64 tiles
  gemm_bt<float, true, 2><<<dim3(64, 16, 1), blk, 0, stream>>>(
      ctxb, Wob, out, bo, 1024, 1024, 1024, 1024, 0, 0, 0, 1.0f);
}

// Round 3
// 366.438 us; speedup vs baseline: 1.0220x; 1.0220x over previous
//
#include <hip/hip_runtime.h>
#include <hip/hip_bf16.h>

typedef __attribute__((ext_vector_type(8))) short bf16x8;
typedef __attribute__((ext_vector_type(4))) float f32x4;

#define AS1 __attribute__((address_space(1)))
#define AS3 __attribute__((address_space(3)))

__device__ __forceinline__ unsigned short f2bf(float f) {
  unsigned u = __float_as_uint(f);
  u += 0x7fff + ((u >> 16) & 1);   // RNE
  return (unsigned short)(u >> 16);
}

__device__ __forceinline__ void gload_lds16(const void* g, void* l) {
  __builtin_amdgcn_global_load_lds((const AS1 unsigned int*)g,
                                   (AS3 unsigned int*)l, 16, 0, 0);
}

// ---------------------------------------------------------------------------
// C[M,N] = scale * (A[M,K] @ Bt[N,K]^T) + bias.  A,Bt bf16 row-major,
// C fp32 or bf16(ushort). Tile 128x128, BK=32, 256 thr = 4 waves (2x2),
// each wave 4x4 of 16x16x32 MFMA. global_load_lds width-16 staging (m97)
// with XOR chunk swizzle (8-way LDS bank conflict -> ~2-way).
// If SPLIT: output cols are split into 1024-wide arrays spaced sC apart
// (used to de-interleave fused QKV); bias still indexed by global col.
// ---------------------------------------------------------------------------
template <typename OutT, bool BIAS, bool SPLIT>
__global__ __launch_bounds__(256) void gemm_bt(
    const unsigned short* __restrict__ A,
    const unsigned short* __restrict__ Bt,
    OutT* __restrict__ C,
    const float* __restrict__ bias,
    int Kd, int lda, int ldb, int ldc,
    long sA, long sB, long sC,
    float scale) {
  __shared__ unsigned short ldsA[128 * 32];
  __shared__ unsigned short ldsB[128 * 32];
  const int bz = blockIdx.z;
  A  += (size_t)bz * sA + (size_t)blockIdx.x * 128 * lda;
  Bt += (size_t)bz * sB + (size_t)blockIdx.y * 128 * ldb;

  const int tid  = threadIdx.x;
  const int wave = tid >> 6;
  const int lane = tid & 63;
  const int wm   = (wave >> 1) * 64;   // wave row offset
  const int wn   = (wave & 1) * 64;    // wave col offset
  const int quad = lane >> 4;
  const int l16  = lane & 15;
  const int srow = wave * 16 + (lane >> 2);  // staging row
  // global chunk this lane fetches (stage-side swizzle)
  const int cg   = ((lane & 3) ^ ((lane >> 2) & 3) ^ (lane >> 4)) * 8;
  // LDS chunk to read for k-chunk `quad` (read-side inverse swizzle)
  const int prd  = (quad ^ (l16 & 3) ^ ((l16 >> 2) & 3)) * 8;

  f32x4 acc[4][4] = {};

  for (int k0 = 0; k0 < Kd; k0 += 32) {
    __syncthreads();
    gload_lds16(A  + (size_t)srow * lda + k0 + cg,        (char*)ldsA + wave * 1024);
    gload_lds16(A  + (size_t)(srow + 64) * lda + k0 + cg, (char*)ldsA + 4096 + wave * 1024);
    gload_lds16(Bt + (size_t)srow * ldb + k0 + cg,        (char*)ldsB + wave * 1024);
    gload_lds16(Bt + (size_t)(srow + 64) * ldb + k0 + cg, (char*)ldsB + 4096 + wave * 1024);
    __syncthreads();

    bf16x8 af[4], bfr[4];
#pragma unroll
    for (int i = 0; i < 4; ++i)
      af[i] = *(const bf16x8*)&ldsA[(wm + i * 16 + l16) * 32 + prd];
#pragma unroll
    for (int j = 0; j < 4; ++j)
      bfr[j] = *(const bf16x8*)&ldsB[(wn + j * 16 + l16) * 32 + prd];
#pragma unroll
    for (int i = 0; i < 4; ++i)
#pragma unroll
      for (int j = 0; j < 4; ++j)
        acc[i][j] = __builtin_amdgcn_mfma_f32_16x16x32_bf16(af[i], bfr[j], acc[i][j], 0, 0, 0);
  }

  const int row0 = blockIdx.x * 128 + wm;
  int col0glob = blockIdx.y * 128 + wn;   // for bias
  int col0;
  if constexpr (SPLIT) {
    C += (size_t)((blockIdx.y * 128) >> 10) * sC;
    col0 = ((blockIdx.y * 128) & 1023) + wn;
  } else {
    C += (size_t)bz * sC;
    col0 = col0glob;
  }
#pragma unroll
  for (int i = 0; i < 4; ++i) {
#pragma unroll
    for (int j = 0; j < 4; ++j) {
      const int col = col0 + j * 16 + l16;
      const float bv = BIAS ? bias[col0glob + j * 16 + l16] : 0.0f;
#pragma unroll
      for (int r = 0; r < 4; ++r) {
        const int row = row0 + i * 16 + quad * 4 + r;
        const float v = acc[i][j][r] * scale + bv;
        if constexpr (sizeof(OutT) == 4)
          C[(size_t)row * ldc + col] = v;
        else
          C[(size_t)row * ldc + col] = (OutT)f2bf(v);
      }
    }
  }
}

// fp32 -> bf16 flat convert (4 elems/thread)
__global__ void cvt_x(const float* __restrict__ in, unsigned short* __restrict__ out, int n4) {
  const int i = blockIdx.x * blockDim.x + threadIdx.x;
  if (i < n4) {
    const float4 v = ((const float4*)in)[i];
    uint2 o;
    o.x = (unsigned)f2bf(v.x) | ((unsigned)f2bf(v.y) << 16);
    o.y = (unsigned)f2bf(v.z) | ((unsigned)f2bf(v.w) << 16);
    ((uint2*)out)[i] = o;
  }
}

// fp32 [rows][cols] -> bf16 transposed [cols][rows]. block (64,4), 64x64 tiles.
__global__ void cvtT_w(const float* __restrict__ in, unsigned short* __restrict__ out,
                       int rows, int cols) {
  __shared__ unsigned short tile[64][65];
  const int r0 = blockIdx.y * 64, c0 = blockIdx.x * 64;
  for (int i = threadIdx.y; i < 64; i += 4)
    tile[i][threadIdx.x] = f2bf(in[(size_t)(r0 + i) * cols + c0 + threadIdx.x]);
  __syncthreads();
  for (int i = threadIdx.y; i < 64; i += 4)
    out[(size_t)(c0 + i) * rows + r0 + threadIdx.x] = tile[threadIdx.x][i];
}

// bf16 [b][rows][cols] -> [b][cols][rows]
__global__ void transpose_bf16(const unsigned short* __restrict__ in,
                               unsigned short* __restrict__ out, int rows, int cols) {
  __shared__ unsigned short tile[64][65];
  const int b = blockIdx.z;
  in  += (size_t)b * rows * cols;
  out += (size_t)b * rows * cols;
  const int r0 = blockIdx.y * 64, c0 = blockIdx.x * 64;
  for (int i = threadIdx.y; i < 64; i += 4)
    tile[i][threadIdx.x] = in[(size_t)(r0 + i) * cols + c0 + threadIdx.x];
  __syncthreads();
  for (int i = threadIdx.y; i < 64; i += 4)
    out[(size_t)(c0 + i) * rows + r0 + threadIdx.x] = tile[threadIdx.x][i];
}

// One block per row of 2048 fp32 scores; softmax in fp32, written in place
// as bf16 (row stride 4096 bf16 elems).
__global__ __launch_bounds__(256) void softmax_inplace(float* __restrict__ scores) {
  float* p = scores + (size_t)blockIdx.x * 2048;
  const int t = threadIdx.x;
  float4 v0 = ((const float4*)p)[t * 2];
  float4 v1 = ((const float4*)p)[t * 2 + 1];

  float m = fmaxf(fmaxf(fmaxf(v0.x, v0.y), fmaxf(v0.z, v0.w)),
                  fmaxf(fmaxf(v1.x, v1.y), fmaxf(v1.z, v1.w)));
#pragma unroll
  for (int off = 32; off; off >>= 1) m = fmaxf(m, __shfl_xor(m, off, 64));

  __shared__ float red[4];
  __shared__ float bcast[2];
  const int wave = t >> 6, lane = t & 63;
  if (lane == 0) red[wave] = m;
  __syncthreads();
  if (t == 0) bcast[0] = fmaxf(fmaxf(red[0], red[1]), fmaxf(red[2], red[3]));
  __syncthreads();
  m = bcast[0];

  v0.x = __expf(v0.x - m); v0.y = __expf(v0.y - m);
  v0.z = __expf(v0.z - m); v0.w = __expf(v0.w - m);
  v1.x = __expf(v1.x - m); v1.y = __expf(v1.y - m);
  v1.z = __expf(v1.z - m); v1.w = __expf(v1.w - m);

  float s = v0.x + v0.y + v0.z + v0.w + v1.x + v1.y + v1.z + v1.w;
#pragma unroll
  for (int off = 32; off; off >>= 1) s += __shfl_xor(s, off, 64);
  if (lane == 0) red[wave] = s;
  __syncthreads();
  if (t == 0) bcast[1] = red[0] + red[1] + red[2] + red[3];
  __syncthreads();
  const float inv = 1.0f / bcast[1];

  uint4 ov;
  ov.x = (unsigned)f2bf(v0.x * inv) | ((unsigned)f2bf(v0.y * inv) << 16);
  ov.y = (unsigned)f2bf(v0.z * inv) | ((unsigned)f2bf(v0.w * inv) << 16);
  ov.z = (unsigned)f2bf(v1.x * inv) | ((unsigned)f2bf(v1.y * inv) << 16);
  ov.w = (unsigned)f2bf(v1.z * inv) | ((unsigned)f2bf(v1.w * inv) << 16);
  ((uint4*)p)[t] = ov;
}

// ---------------------------------------------------------------------------
extern "C" void kernel_launch(void* const* d_in, const int* in_sizes, int n_in,
                              void* d_out, int out_size, void* d_ws, size_t ws_size,
                              hipStream_t stream) {
  const float* x  = (const float*)d_in[0];
  const float* Wq = (const float*)d_in[1];
  const float* bq = (const float*)d_in[2];
  const float* Wk = (const float*)d_in[3];
  const float* bk = (const float*)d_in[4];
  const float* Wv = (const float*)d_in[5];
  const float* bv = (const float*)d_in[6];
  const float* Wo = (const float*)d_in[7];
  const float* bo = (const float*)d_in[8];
  float* out = (float*)d_out;

  char* ws = (char*)d_ws;
  size_t off = 0;
  auto alloc = [&](size_t bytes) { char* p = ws + off; off += (bytes + 255) & ~255UL; return p; };
  unsigned short* xb    = (unsigned short*)alloc(8192UL * 1024 * 2);     // 16 MiB
  unsigned short* Wqkvb = (unsigned short*)alloc(3072UL * 1024 * 2);     // 6 MiB
  unsigned short* Wob   = (unsigned short*)alloc(1024UL * 1024 * 2);     // 2 MiB
  float*          bqkv  = (float*)alloc(3072UL * 4);
  unsigned short* Qb    = (unsigned short*)alloc(8192UL * 1024 * 2);     // 16 MiB
  unsigned short* Kb    = (unsigned short*)alloc(8192UL * 1024 * 2);     // 16 MiB
  unsigned short* Vb    = (unsigned short*)alloc(8192UL * 1024 * 2);     // 16 MiB
  unsigned short* Vtb   = (unsigned short*)alloc(4UL * 1024 * 2048 * 2); // 16 MiB
  unsigned short* ctxb  = (unsigned short*)alloc(8192UL * 1024 * 2);     // 16 MiB
  float*          sc    = (float*)alloc(4UL * 2048 * 2048 * 4);          // 64 MiB

  const dim3 blk(256);

  // converts + weight transposes (QKV weights concatenated in Bt layout)
  cvt_x<<<2097152 / 256, 256, 0, stream>>>(x, xb, 2097152);
  cvtT_w<<<dim3(16, 16), dim3(64, 4), 0, stream>>>(Wq, Wqkvb, 1024, 1024);
  cvtT_w<<<dim3(16, 16), dim3(64, 4), 0, stream>>>(Wk, Wqkvb + 1024 * 1024, 1024, 1024);
  cvtT_w<<<dim3(16, 16), dim3(64, 4), 0, stream>>>(Wv, Wqkvb + 2048 * 1024, 1024, 1024);
  cvtT_w<<<dim3(16, 16), dim3(64, 4), 0, stream>>>(Wo, Wob, 1024, 1024);
  hipMemcpyAsync(bqkv,        bq, 1024 * 4, hipMemcpyDeviceToDevice, stream);
  hipMemcpyAsync(bqkv + 1024, bk, 1024 * 4, hipMemcpyDeviceToDevice, stream);
  hipMemcpyAsync(bqkv + 2048, bv, 1024 * 4, hipMemcpyDeviceToDevice, stream);

  // fused QKV projection, output split into compact Q|K|V (stride 1024).
  // Qb,Kb,Vb are contiguous: split stride = 8192*1024 elems.
  gemm_bt<unsigned short, true, true><<<dim3(64, 24, 1), blk, 0, stream>>>(
      xb, Wqkvb, Qb, bqkv, 1024, 1024, 1024, 1024, 0, 0, 8192L * 1024, 1.0f);

  // V^T per batch: [4][1024][2048]
  transpose_bf16<<<dim3(16, 32, 4), dim3(64, 4), 0, stream>>>(Vb, Vtb, 2048, 1024);

  // scores = (Q @ K^T) / 32, fp32, per batch
  gemm_bt<float, false, false><<<dim3(16, 16, 4), blk, 0, stream>>>(
      Qb, Kb, sc, nullptr, 1024, 1024, 1024, 2048,
      2048L * 1024, 2048L * 1024, 2048L * 2048, 0.03125f);

  // softmax rows (in-place fp32 -> bf16, row stride 4096 bf16)
  softmax_inplace<<<8192, 256, 0, stream>>>(sc);

  // ctx = attn @ V  (attn bf16 lda=4096, Vt is Bt layout)
  gemm_bt<unsigned short, false, false><<<dim3(16, 8, 4), blk, 0, stream>>>(
      (unsigned short*)sc, Vtb, ctxb, nullptr, 2048, 4096, 2048, 1024,
      2048L * 4096, 1024L * 2048, 2048L * 1024, 1.0f);

  // out = ctx @ Wo + bo (fp32 out)
  gemm_bt<float, true, false><<<dim3(64, 8, 1), blk, 0, stream>>>(
      ctxb, Wob, out, bo, 1024, 1024, 1024, 1024, 0, 0, 0, 1.0f);
}

// Round 4
// 328.504 us; speedup vs baseline: 1.1401x; 1.1155x over previous
//
#include <hip/hip_runtime.h>
#include <hip/hip_bf16.h>

typedef __attribute__((ext_vector_type(8))) short bf16x8;
typedef __attribute__((ext_vector_type(16))) float f32x16;

#define AS1 __attribute__((address_space(1)))
#define AS3 __attribute__((address_space(3)))

__device__ __forceinline__ unsigned short f2bf(float f) {
  unsigned u = __float_as_uint(f);
  u += 0x7fff + ((u >> 16) & 1);   // RNE
  return (unsigned short)(u >> 16);
}

__device__ __forceinline__ void gload_lds16(const void* g, void* l) {
  __builtin_amdgcn_global_load_lds((const AS1 unsigned int*)g,
                                   (AS3 unsigned int*)l, 16, 0, 0);
}

// ---------------------------------------------------------------------------
// C[M,N] = scale * (A[M,K] @ Bt[N,K]^T) + bias.  A,Bt bf16 row-major,
// C fp32 or bf16(ushort). Tile 128x128, BK=32, 256 thr = 4 waves (2x2),
// each wave 2x2 of 32x32x16 MFMA (64x64). global_load_lds width-16 staging
// with XOR chunk swizzle (LDS chunk p of row r holds global chunk
// p ^ (r&3) ^ ((r>>2)&3)).
// If SPLIT: output cols split into 1024-wide arrays spaced sC apart
// (de-interleaves fused QKV); bias still indexed by global col.
// ---------------------------------------------------------------------------
template <typename OutT, bool BIAS, bool SPLIT>
__global__ __launch_bounds__(256) void gemm_bt(
    const unsigned short* __restrict__ A,
    const unsigned short* __restrict__ Bt,
    OutT* __restrict__ C,
    const float* __restrict__ bias,
    int Kd, int lda, int ldb, int ldc,
    long sA, long sB, long sC,
    float scale) {
  __shared__ unsigned short ldsA[128 * 32];
  __shared__ unsigned short ldsB[128 * 32];
  const int bz = blockIdx.z;
  A  += (size_t)bz * sA + (size_t)blockIdx.x * 128 * lda;
  Bt += (size_t)bz * sB + (size_t)blockIdx.y * 128 * ldb;

  const int tid  = threadIdx.x;
  const int wave = tid >> 6;
  const int lane = tid & 63;
  const int wm   = (wave >> 1) * 64;   // wave row offset
  const int wn   = (wave & 1) * 64;    // wave col offset
  const int l32  = lane & 31;
  const int half = lane >> 5;
  const int srow = wave * 16 + (lane >> 2);  // staging row
  // global chunk this lane fetches (stage-side swizzle)
  const int cg   = ((lane & 3) ^ ((lane >> 2) & 3) ^ (lane >> 4)) * 8;
  // read-side swizzled chunk position (depends only on l32, per k-half h):
  // p(h) = (2h + half) ^ (l32&3) ^ ((l32>>2)&3)   (wm, t*32 are 0 mod 16)
  const int pswz = (l32 & 3) ^ ((l32 >> 2) & 3);

  f32x16 acc[2][2] = {};

  for (int k0 = 0; k0 < Kd; k0 += 32) {
    __syncthreads();
    gload_lds16(A  + (size_t)srow * lda + k0 + cg,        (char*)ldsA + wave * 1024);
    gload_lds16(A  + (size_t)(srow + 64) * lda + k0 + cg, (char*)ldsA + 4096 + wave * 1024);
    gload_lds16(Bt + (size_t)srow * ldb + k0 + cg,        (char*)ldsB + wave * 1024);
    gload_lds16(Bt + (size_t)(srow + 64) * ldb + k0 + cg, (char*)ldsB + 4096 + wave * 1024);
    __syncthreads();

    bf16x8 af[2][2], bfr[2][2];
#pragma unroll
    for (int t = 0; t < 2; ++t)
#pragma unroll
      for (int h = 0; h < 2; ++h) {
        const int p = ((2 * h + half) ^ pswz) * 8;
        af[t][h]  = *(const bf16x8*)&ldsA[(wm + t * 32 + l32) * 32 + p];
        bfr[t][h] = *(const bf16x8*)&ldsB[(wn + t * 32 + l32) * 32 + p];
      }
#pragma unroll
    for (int t = 0; t < 2; ++t)
#pragma unroll
      for (int u = 0; u < 2; ++u) {
        acc[t][u] = __builtin_amdgcn_mfma_f32_32x32x16_bf16(af[t][0], bfr[u][0], acc[t][u], 0, 0, 0);
        acc[t][u] = __builtin_amdgcn_mfma_f32_32x32x16_bf16(af[t][1], bfr[u][1], acc[t][u], 0, 0, 0);
      }
  }

  const int row0 = blockIdx.x * 128 + wm;
  const int col0glob = blockIdx.y * 128 + wn;   // for bias
  int col0;
  if constexpr (SPLIT) {
    C += (size_t)((blockIdx.y * 128) >> 10) * sC;
    col0 = ((blockIdx.y * 128) & 1023) + wn;
  } else {
    C += (size_t)bz * sC;
    col0 = col0glob;
  }
#pragma unroll
  for (int t = 0; t < 2; ++t) {
#pragma unroll
    for (int u = 0; u < 2; ++u) {
      const int col = col0 + u * 32 + l32;
      const float bv = BIAS ? bias[col0glob + u * 32 + l32] : 0.0f;
#pragma unroll
      for (int r = 0; r < 16; ++r) {
        const int row = row0 + t * 32 + (r & 3) + 8 * (r >> 2) + 4 * half;
        const float v = acc[t][u][r] * scale + bv;
        if constexpr (sizeof(OutT) == 4)
          C[(size_t)row * ldc + col] = v;
        else
          C[(size_t)row * ldc + col] = (OutT)f2bf(v);
      }
    }
  }
}

// fp32 -> bf16 flat convert (4 elems/thread)
__global__ void cvt_x(const float* __restrict__ in, unsigned short* __restrict__ out, int n4) {
  const int i = blockIdx.x * blockDim.x + threadIdx.x;
  if (i < n4) {
    const float4 v = ((const float4*)in)[i];
    uint2 o;
    o.x = (unsigned)f2bf(v.x) | ((unsigned)f2bf(v.y) << 16);
    o.y = (unsigned)f2bf(v.z) | ((unsigned)f2bf(v.w) << 16);
    ((uint2*)out)[i] = o;
  }
}

// All 4 weight matrices (1024x1024 fp32) -> bf16 transposed, one launch.
// grid (16,16,4); z selects source/dest.
__global__ void cvtT_w4(const float* __restrict__ Wq, const float* __restrict__ Wk,
                        const float* __restrict__ Wv, const float* __restrict__ Wo,
                        unsigned short* __restrict__ Wqkvb, unsigned short* __restrict__ Wob) {
  __shared__ unsigned short tile[64][65];
  const int z = blockIdx.z;
  const float* in = (z == 0) ? Wq : (z == 1) ? Wk : (z == 2) ? Wv : Wo;
  unsigned short* out = (z == 3) ? Wob : Wqkvb + (size_t)z * 1024 * 1024;
  const int r0 = blockIdx.y * 64, c0 = blockIdx.x * 64;
  for (int i = threadIdx.y; i < 64; i += 4)
    tile[i][threadIdx.x] = f2bf(in[(size_t)(r0 + i) * 1024 + c0 + threadIdx.x]);
  __syncthreads();
  for (int i = threadIdx.y; i < 64; i += 4)
    out[(size_t)(c0 + i) * 1024 + r0 + threadIdx.x] = tile[threadIdx.x][i];
}

// concat bq|bk|bv into bqkv (3 blocks x 256 thr, 4 elems each)
__global__ void concat_bias(const float* __restrict__ bq, const float* __restrict__ bk,
                            const float* __restrict__ bv, float* __restrict__ dst) {
  const int z = blockIdx.x;
  const float* src = (z == 0) ? bq : (z == 1) ? bk : bv;
  const int i = threadIdx.x;
  ((float4*)(dst + z * 1024))[i] = ((const float4*)src)[i];
}

// bf16 [b][rows][cols] -> [b][cols][rows]
__global__ void transpose_bf16(const unsigned short* __restrict__ in,
                               unsigned short* __restrict__ out, int rows, int cols) {
  __shared__ unsigned short tile[64][65];
  const int b = blockIdx.z;
  in  += (size_t)b * rows * cols;
  out += (size_t)b * rows * cols;
  const int r0 = blockIdx.y * 64, c0 = blockIdx.x * 64;
  for (int i = threadIdx.y; i < 64; i += 4)
    tile[i][threadIdx.x] = in[(size_t)(r0 + i) * cols + c0 + threadIdx.x];
  __syncthreads();
  for (int i = threadIdx.y; i < 64; i += 4)
    out[(size_t)(c0 + i) * rows + r0 + threadIdx.x] = tile[threadIdx.x][i];
}

// One block per row of 2048 fp32 scores; softmax in fp32, written in place
// as bf16 (row stride 4096 bf16 elems).
__global__ __launch_bounds__(256) void softmax_inplace(float* __restrict__ scores) {
  float* p = scores + (size_t)blockIdx.x * 2048;
  const int t = threadIdx.x;
  float4 v0 = ((const float4*)p)[t * 2];
  float4 v1 = ((const float4*)p)[t * 2 + 1];

  float m = fmaxf(fmaxf(fmaxf(v0.x, v0.y), fmaxf(v0.z, v0.w)),
                  fmaxf(fmaxf(v1.x, v1.y), fmaxf(v1.z, v1.w)));
#pragma unroll
  for (int off = 32; off; off >>= 1) m = fmaxf(m, __shfl_xor(m, off, 64));

  __shared__ float red[4];
  __shared__ float bcast[2];
  const int wave = t >> 6, lane = t & 63;
  if (lane == 0) red[wave] = m;
  __syncthreads();
  if (t == 0) bcast[0] = fmaxf(fmaxf(red[0], red[1]), fmaxf(red[2], red[3]));
  __syncthreads();
  m = bcast[0];

  v0.x = __expf(v0.x - m); v0.y = __expf(v0.y - m);
  v0.z = __expf(v0.z - m); v0.w = __expf(v0.w - m);
  v1.x = __expf(v1.x - m); v1.y = __expf(v1.y - m);
  v1.z = __expf(v1.z - m); v1.w = __expf(v1.w - m);

  float s = v0.x + v0.y + v0.z + v0.w + v1.x + v1.y + v1.z + v1.w;
#pragma unroll
  for (int off = 32; off; off >>= 1) s += __shfl_xor(s, off, 64);
  if (lane == 0) red[wave] = s;
  __syncthreads();
  if (t == 0) bcast[1] = red[0] + red[1] + red[2] + red[3];
  __syncthreads();
  const float inv = 1.0f / bcast[1];

  uint4 ov;
  ov.x = (unsigned)f2bf(v0.x * inv) | ((unsigned)f2bf(v0.y * inv) << 16);
  ov.y = (unsigned)f2bf(v0.z * inv) | ((unsigned)f2bf(v0.w * inv) << 16);
  ov.z = (unsigned)f2bf(v1.x * inv) | ((unsigned)f2bf(v1.y * inv) << 16);
  ov.w = (unsigned)f2bf(v1.z * inv) | ((unsigned)f2bf(v1.w * inv) << 16);
  ((uint4*)p)[t] = ov;
}

// ---------------------------------------------------------------------------
extern "C" void kernel_launch(void* const* d_in, const int* in_sizes, int n_in,
                              void* d_out, int out_size, void* d_ws, size_t ws_size,
                              hipStream_t stream) {
  const float* x  = (const float*)d_in[0];
  const float* Wq = (const float*)d_in[1];
  const float* bq = (const float*)d_in[2];
  const float* Wk = (const float*)d_in[3];
  const float* bk = (const float*)d_in[4];
  const float* Wv = (const float*)d_in[5];
  const float* bv = (const float*)d_in[6];
  const float* Wo = (const float*)d_in[7];
  const float* bo = (const float*)d_in[8];
  float* out = (float*)d_out;

  char* ws = (char*)d_ws;
  size_t off = 0;
  auto alloc = [&](size_t bytes) { char* p = ws + off; off += (bytes + 255) & ~255UL; return p; };
  unsigned short* xb    = (unsigned short*)alloc(8192UL * 1024 * 2);     // 16 MiB
  unsigned short* Wqkvb = (unsigned short*)alloc(3072UL * 1024 * 2);     // 6 MiB
  unsigned short* Wob   = (unsigned short*)alloc(1024UL * 1024 * 2);     // 2 MiB
  float*          bqkv  = (float*)alloc(3072UL * 4);
  unsigned short* Qb    = (unsigned short*)alloc(8192UL * 1024 * 2);     // 16 MiB
  unsigned short* Kb    = (unsigned short*)alloc(8192UL * 1024 * 2);     // 16 MiB
  unsigned short* Vb    = (unsigned short*)alloc(8192UL * 1024 * 2);     // 16 MiB
  unsigned short* Vtb   = (unsigned short*)alloc(4UL * 1024 * 2048 * 2); // 16 MiB
  unsigned short* ctxb  = (unsigned short*)alloc(8192UL * 1024 * 2);     // 16 MiB
  float*          sc    = (float*)alloc(4UL * 2048 * 2048 * 4);          // 64 MiB

  const dim3 blk(256);

  // input convert + all weight transposes + bias concat
  cvt_x<<<2097152 / 256, 256, 0, stream>>>(x, xb, 2097152);
  cvtT_w4<<<dim3(16, 16, 4), dim3(64, 4), 0, stream>>>(Wq, Wk, Wv, Wo, Wqkvb, Wob);
  concat_bias<<<3, 256, 0, stream>>>(bq, bk, bv, bqkv);

  // fused QKV projection, output split into compact Q|K|V (stride 1024).
  gemm_bt<unsigned short, true, true><<<dim3(64, 24, 1), blk, 0, stream>>>(
      xb, Wqkvb, Qb, bqkv, 1024, 1024, 1024, 1024, 0, 0, 8192L * 1024, 1.0f);

  // V^T per batch: [4][1024][2048]
  transpose_bf16<<<dim3(16, 32, 4), dim3(64, 4), 0, stream>>>(Vb, Vtb, 2048, 1024);

  // scores = (Q @ K^T) / 32, fp32, per batch
  gemm_bt<float, false, false><<<dim3(16, 16, 4), blk, 0, stream>>>(
      Qb, Kb, sc, nullptr, 1024, 1024, 1024, 2048,
      2048L * 1024, 2048L * 1024, 2048L * 2048, 0.03125f);

  // softmax rows (in-place fp32 -> bf16, row stride 4096 bf16)
  softmax_inplace<<<8192, 256, 0, stream>>>(sc);

  // ctx = attn @ V  (attn bf16 lda=4096, Vt is Bt layout)
  gemm_bt<unsigned short, false, false><<<dim3(16, 8, 4), blk, 0, stream>>>(
      (unsigned short*)sc, Vtb, ctxb, nullptr, 2048, 4096, 2048, 1024,
      2048L * 4096, 1024L * 2048, 2048L * 1024, 1.0f);

  // out = ctx @ Wo + bo (fp32 out)
  gemm_bt<float, true, false><<<dim3(64, 8, 1), blk, 0, stream>>>(
      ctxb, Wob, out, bo, 1024, 1024, 1024, 1024, 0, 0, 0, 1.0f);
}

// Round 5
// 317.557 us; speedup vs baseline: 1.1794x; 1.0345x over previous
//
#include <hip/hip_runtime.h>
#include <hip/hip_bf16.h>

typedef __attribute__((ext_vector_type(8))) short bf16x8;
typedef __attribute__((ext_vector_type(16))) float f32x16;

#define AS1 __attribute__((address_space(1)))
#define AS3 __attribute__((address_space(3)))

__device__ __forceinline__ unsigned short f2bf(float f) {
  unsigned u = __float_as_uint(f);
  u += 0x7fff + ((u >> 16) & 1);   // RNE
  return (unsigned short)(u >> 16);
}

__device__ __forceinline__ void gload_lds16(const void* g, void* l) {
  __builtin_amdgcn_global_load_lds((const AS1 unsigned int*)g,
                                   (AS3 unsigned int*)l, 16, 0, 0);
}

// ---------------------------------------------------------------------------
// C[M,N] = scale * (A[M,K] @ Bt[N,K]^T) + bias.  A,Bt bf16 row-major,
// C fp32 or bf16(ushort). Block tile 128 x (NJ*64), BK=32, 256 thr = 4 waves
// (2x2), wave tile 64 x (NJ*32) of 32x32x16 MFMA.
// Double-buffered LDS: prefetch of tile k+1 issued right after the barrier,
// so the vmcnt(0) drain at the NEXT barrier overlaps the whole compute phase.
// XOR chunk swizzle: LDS chunk p of row r holds global chunk
// p ^ (r&3) ^ ((r>>2)&3)  -> zero bank conflicts (verified round 4).
// If SPLIT: output cols split into 1024-wide arrays spaced sC apart
// (de-interleaves fused QKV); bias still indexed by global col.
// ---------------------------------------------------------------------------
template <typename OutT, bool BIAS, bool SPLIT, int NJ>
__global__ __launch_bounds__(256, (NJ == 4) ? 2 : 3) void gemm_bt(
    const unsigned short* __restrict__ A,
    const unsigned short* __restrict__ Bt,
    OutT* __restrict__ C,
    const float* __restrict__ bias,
    int Kd, int lda, int ldb, int ldc,
    long sA, long sB, long sC,
    float scale) {
  constexpr int BN    = NJ * 64;     // block N width
  constexpr int ROWS  = 128 + BN;    // staged rows per k-tile (A then B)
  constexpr int SLOTS = ROWS / 16;   // 1-KB staging slots (16 rows each)
  __shared__ unsigned short lds[2][ROWS * 32];

  const int bz = blockIdx.z;
  A  += (size_t)bz * sA + (size_t)blockIdx.x * 128 * lda;
  Bt += (size_t)bz * sB + (size_t)blockIdx.y * BN * ldb;

  const int tid  = threadIdx.x;
  const int wave = tid >> 6;
  const int lane = tid & 63;
  const int wm   = (wave >> 1) * 64;         // wave row offset
  const int wn   = (wave & 1) * (NJ * 32);   // wave col offset
  const int l32  = lane & 31;
  const int half = lane >> 5;
  // stage-side swizzle: this lane fetches global chunk cg/8 of its row
  const int cg   = ((lane & 3) ^ ((lane >> 2) & 3) ^ (lane >> 4)) * 8;
  // read-side: LDS chunk for global chunk (2h+half) at rows == l32 (mod 16)
  const int pswz = (l32 & 3) ^ ((l32 >> 2) & 3);

  auto stage = [&](int k0, int b) {
#pragma unroll
    for (int j = 0; j < SLOTS / 4; ++j) {
      const int s = wave + 4 * j;            // slot (wave-uniform)
      const int r = s * 16 + (lane >> 2);    // row in concat(A,B) space
      const unsigned short* src = (s < 8) ? (A + (size_t)r * lda)
                                          : (Bt + (size_t)(r - 128) * ldb);
      gload_lds16(src + k0 + cg, (char*)&lds[b][0] + s * 1024);
    }
  };

  f32x16 acc[2][NJ] = {};

  stage(0, 0);
  int cur = 0;
  for (int k0 = 0; k0 < Kd; k0 += 32) {
    __syncthreads();                         // drains prefetch of lds[cur]
    if (k0 + 32 < Kd) stage(k0 + 32, cur ^ 1);

    const unsigned short* base = &lds[cur][0];
    bf16x8 af[2][2], bfr[NJ][2];
#pragma unroll
    for (int t = 0; t < 2; ++t)
#pragma unroll
      for (int h = 0; h < 2; ++h) {
        const int p = ((2 * h + half) ^ pswz) * 8;
        af[t][h] = *(const bf16x8*)&base[(wm + t * 32 + l32) * 32 + p];
      }
#pragma unroll
    for (int u = 0; u < NJ; ++u)
#pragma unroll
      for (int h = 0; h < 2; ++h) {
        const int p = ((2 * h + half) ^ pswz) * 8;
        bfr[u][h] = *(const bf16x8*)&base[(128 + wn + u * 32 + l32) * 32 + p];
      }
#pragma unroll
    for (int t = 0; t < 2; ++t)
#pragma unroll
      for (int u = 0; u < NJ; ++u) {
        acc[t][u] = __builtin_amdgcn_mfma_f32_32x32x16_bf16(af[t][0], bfr[u][0], acc[t][u], 0, 0, 0);
        acc[t][u] = __builtin_amdgcn_mfma_f32_32x32x16_bf16(af[t][1], bfr[u][1], acc[t][u], 0, 0, 0);
      }
    cur ^= 1;
  }

  const int row0 = blockIdx.x * 128 + wm;
  const int colb = blockIdx.y * BN;
  int col0;
  if constexpr (SPLIT) {
    C += (size_t)(colb >> 10) * sC;
    col0 = (colb & 1023) + wn;
  } else {
    C += (size_t)bz * sC;
    col0 = colb + wn;
  }
#pragma unroll
  for (int t = 0; t < 2; ++t) {
#pragma unroll
    for (int u = 0; u < NJ; ++u) {
      const int col = col0 + u * 32 + l32;
      const float bv = BIAS ? bias[colb + wn + u * 32 + l32] : 0.0f;
#pragma unroll
      for (int r = 0; r < 16; ++r) {
        const int row = row0 + t * 32 + (r & 3) + 8 * (r >> 2) + 4 * half;
        const float v = acc[t][u][r] * scale + bv;
        if constexpr (sizeof(OutT) == 4)
          C[(size_t)row * ldc + col] = v;
        else
          C[(size_t)row * ldc + col] = (OutT)f2bf(v);
      }
    }
  }
}

// fp32 -> bf16 flat convert (4 elems/thread)
__global__ void cvt_x(const float* __restrict__ in, unsigned short* __restrict__ out, int n4) {
  const int i = blockIdx.x * blockDim.x + threadIdx.x;
  if (i < n4) {
    const float4 v = ((const float4*)in)[i];
    uint2 o;
    o.x = (unsigned)f2bf(v.x) | ((unsigned)f2bf(v.y) << 16);
    o.y = (unsigned)f2bf(v.z) | ((unsigned)f2bf(v.w) << 16);
    ((uint2*)out)[i] = o;
  }
}

// All 4 weight matrices (1024x1024 fp32) -> bf16 transposed, one launch.
__global__ void cvtT_w4(const float* __restrict__ Wq, const float* __restrict__ Wk,
                        const float* __restrict__ Wv, const float* __restrict__ Wo,
                        unsigned short* __restrict__ Wqkvb, unsigned short* __restrict__ Wob) {
  __shared__ unsigned short tile[64][65];
  const int z = blockIdx.z;
  const float* in = (z == 0) ? Wq : (z == 1) ? Wk : (z == 2) ? Wv : Wo;
  unsigned short* out = (z == 3) ? Wob : Wqkvb + (size_t)z * 1024 * 1024;
  const int r0 = blockIdx.y * 64, c0 = blockIdx.x * 64;
  for (int i = threadIdx.y; i < 64; i += 4)
    tile[i][threadIdx.x] = f2bf(in[(size_t)(r0 + i) * 1024 + c0 + threadIdx.x]);
  __syncthreads();
  for (int i = threadIdx.y; i < 64; i += 4)
    out[(size_t)(c0 + i) * 1024 + r0 + threadIdx.x] = tile[threadIdx.x][i];
}

// concat bq|bk|bv into bqkv
__global__ void concat_bias(const float* __restrict__ bq, const float* __restrict__ bk,
                            const float* __restrict__ bv, float* __restrict__ dst) {
  const int z = blockIdx.x;
  const float* src = (z == 0) ? bq : (z == 1) ? bk : bv;
  const int i = threadIdx.x;
  ((float4*)(dst + z * 1024))[i] = ((const float4*)src)[i];
}

// bf16 [b][rows][cols] -> [b][cols][rows]
__global__ void transpose_bf16(const unsigned short* __restrict__ in,
                               unsigned short* __restrict__ out, int rows, int cols) {
  __shared__ unsigned short tile[64][65];
  const int b = blockIdx.z;
  in  += (size_t)b * rows * cols;
  out += (size_t)b * rows * cols;
  const int r0 = blockIdx.y * 64, c0 = blockIdx.x * 64;
  for (int i = threadIdx.y; i < 64; i += 4)
    tile[i][threadIdx.x] = in[(size_t)(r0 + i) * cols + c0 + threadIdx.x];
  __syncthreads();
  for (int i = threadIdx.y; i < 64; i += 4)
    out[(size_t)(c0 + i) * rows + r0 + threadIdx.x] = tile[threadIdx.x][i];
}

// One block per row of 2048 fp32 scores; softmax in fp32, written in place
// as bf16 (row stride 4096 bf16 elems).
__global__ __launch_bounds__(256) void softmax_inplace(float* __restrict__ scores) {
  float* p = scores + (size_t)blockIdx.x * 2048;
  const int t = threadIdx.x;
  float4 v0 = ((const float4*)p)[t * 2];
  float4 v1 = ((const float4*)p)[t * 2 + 1];

  float m = fmaxf(fmaxf(fmaxf(v0.x, v0.y), fmaxf(v0.z, v0.w)),
                  fmaxf(fmaxf(v1.x, v1.y), fmaxf(v1.z, v1.w)));
#pragma unroll
  for (int off = 32; off; off >>= 1) m = fmaxf(m, __shfl_xor(m, off, 64));

  __shared__ float red[4];
  __shared__ float bcast[2];
  const int wave = t >> 6, lane = t & 63;
  if (lane == 0) red[wave] = m;
  __syncthreads();
  if (t == 0) bcast[0] = fmaxf(fmaxf(red[0], red[1]), fmaxf(red[2], red[3]));
  __syncthreads();
  m = bcast[0];

  v0.x = __expf(v0.x - m); v0.y = __expf(v0.y - m);
  v0.z = __expf(v0.z - m); v0.w = __expf(v0.w - m);
  v1.x = __expf(v1.x - m); v1.y = __expf(v1.y - m);
  v1.z = __expf(v1.z - m); v1.w = __expf(v1.w - m);

  float s = v0.x + v0.y + v0.z + v0.w + v1.x + v1.y + v1.z + v1.w;
#pragma unroll
  for (int off = 32; off; off >>= 1) s += __shfl_xor(s, off, 64);
  if (lane == 0) red[wave] = s;
  __syncthreads();
  if (t == 0) bcast[1] = red[0] + red[1] + red[2] + red[3];
  __syncthreads();
  const float inv = 1.0f / bcast[1];

  uint4 ov;
  ov.x = (unsigned)f2bf(v0.x * inv) | ((unsigned)f2bf(v0.y * inv) << 16);
  ov.y = (unsigned)f2bf(v0.z * inv) | ((unsigned)f2bf(v0.w * inv) << 16);
  ov.z = (unsigned)f2bf(v1.x * inv) | ((unsigned)f2bf(v1.y * inv) << 16);
  ov.w = (unsigned)f2bf(v1.z * inv) | ((unsigned)f2bf(v1.w * inv) << 16);
  ((uint4*)p)[t] = ov;
}

// ---------------------------------------------------------------------------
extern "C" void kernel_launch(void* const* d_in, const int* in_sizes, int n_in,
                              void* d_out, int out_size, void* d_ws, size_t ws_size,
                              hipStream_t stream) {
  const float* x  = (const float*)d_in[0];
  const float* Wq = (const float*)d_in[1];
  const float* bq = (const float*)d_in[2];
  const float* Wk = (const float*)d_in[3];
  const float* bk = (const float*)d_in[4];
  const float* Wv = (const float*)d_in[5];
  const float* bv = (const float*)d_in[6];
  const float* Wo = (const float*)d_in[7];
  const float* bo = (const float*)d_in[8];
  float* out = (float*)d_out;

  char* ws = (char*)d_ws;
  size_t off = 0;
  auto alloc = [&](size_t bytes) { char* p = ws + off; off += (bytes + 255) & ~255UL; return p; };
  unsigned short* xb    = (unsigned short*)alloc(8192UL * 1024 * 2);     // 16 MiB
  unsigned short* Wqkvb = (unsigned short*)alloc(3072UL * 1024 * 2);     // 6 MiB
  unsigned short* Wob   = (unsigned short*)alloc(1024UL * 1024 * 2);     // 2 MiB
  float*          bqkv  = (float*)alloc(3072UL * 4);
  unsigned short* Qb    = (unsigned short*)alloc(8192UL * 1024 * 2);     // 16 MiB
  unsigned short* Kb    = (unsigned short*)alloc(8192UL * 1024 * 2);     // 16 MiB
  unsigned short* Vb    = (unsigned short*)alloc(8192UL * 1024 * 2);     // 16 MiB
  unsigned short* Vtb   = (unsigned short*)alloc(4UL * 1024 * 2048 * 2); // 16 MiB
  unsigned short* ctxb  = (unsigned short*)alloc(8192UL * 1024 * 2);     // 16 MiB
  float*          sc    = (float*)alloc(4UL * 2048 * 2048 * 4);          // 64 MiB

  const dim3 blk(256);

  // input convert + all weight transposes + bias concat
  cvt_x<<<2097152 / 256, 256, 0, stream>>>(x, xb, 2097152);
  cvtT_w4<<<dim3(16, 16, 4), dim3(64, 4), 0, stream>>>(Wq, Wk, Wv, Wo, Wqkvb, Wob);
  concat_bias<<<3, 256, 0, stream>>>(bq, bk, bv, bqkv);

  // fused QKV projection (NJ=4: 128x256 tiles), split into compact Q|K|V
  gemm_bt<unsigned short, true, true, 4><<<dim3(64, 12, 1), blk, 0, stream>>>(
      xb, Wqkvb, Qb, bqkv, 1024, 1024, 1024, 1024, 0, 0, 8192L * 1024, 1.0f);

  // V^T per batch: [4][1024][2048]
  transpose_bf16<<<dim3(16, 32, 4), dim3(64, 4), 0, stream>>>(Vb, Vtb, 2048, 1024);

  // scores = (Q @ K^T) / 32, fp32, per batch (NJ=4)
  gemm_bt<float, false, false, 4><<<dim3(16, 8, 4), blk, 0, stream>>>(
      Qb, Kb, sc, nullptr, 1024, 1024, 1024, 2048,
      2048L * 1024, 2048L * 1024, 2048L * 2048, 0.03125f);

  // softmax rows (in-place fp32 -> bf16, row stride 4096 bf16)
  softmax_inplace<<<8192, 256, 0, stream>>>(sc);

  // ctx = attn @ V  (attn bf16 lda=4096, Vt is Bt layout) (NJ=2)
  gemm_bt<unsigned short, false, false, 2><<<dim3(16, 8, 4), blk, 0, stream>>>(
      (unsigned short*)sc, Vtb, ctxb, nullptr, 2048, 4096, 2048, 1024,
      2048L * 4096, 1024L * 2048, 2048L * 1024, 1.0f);

  // out = ctx @ Wo + bo (fp32 out) (NJ=2)
  gemm_bt<float, true, false, 2><<<dim3(64, 8, 1), blk, 0, stream>>>(
      ctxb, Wob, out, bo, 1024, 1024, 1024, 1024, 0, 0, 0, 1.0f);
}

// Round 6
// 300.172 us; speedup vs baseline: 1.2477x; 1.0579x over previous
//
#include <hip/hip_runtime.h>
#include <hip/hip_bf16.h>

typedef __attribute__((ext_vector_type(8))) short bf16x8;
typedef __attribute__((ext_vector_type(16))) float f32x16;
typedef __attribute__((ext_vector_type(4))) unsigned short us4;

#define AS1 __attribute__((address_space(1)))
#define AS3 __attribute__((address_space(3)))

__device__ __forceinline__ unsigned short f2bf(float f) {
  unsigned u = __float_as_uint(f);
  u += 0x7fff + ((u >> 16) & 1);   // RNE
  return (unsigned short)(u >> 16);
}

__device__ __forceinline__ float bf2f(unsigned short h) {
  return __uint_as_float((unsigned)h << 16);
}

__device__ __forceinline__ void gload_lds16(const void* g, void* l) {
  __builtin_amdgcn_global_load_lds((const AS1 unsigned int*)g,
                                   (AS3 unsigned int*)l, 16, 0, 0);
}

// ---------------------------------------------------------------------------
// C[M,N] = scale * (A[M,K] @ Bt[N,K]^T) + bias.  A,Bt bf16 row-major,
// C fp32 or bf16(ushort). Block tile 128 x (NJ*64), BK=32, 256 thr = 4 waves
// (2x2), wave tile 64 x (NJ*32) of 32x32x16 MFMA. Double-buffered LDS with
// post-barrier prefetch. XOR chunk swizzle -> zero LDS bank conflicts
// (verified round 4: SQ_LDS_BANK_CONFLICT = 0).
// MODE 0: normal output [bz][M][ldc] (+bz*sC).
// MODE 1: fused-QKV de-interleave: per-32-col granule, piece = gcol>>10;
//   pieces 0,1 (Q,K) -> C + piece*sC, compact [8192][1024];
//   piece 2 (V) -> written TRANSPOSED to Vt[b][d][2048] (b = row>>11).
// ---------------------------------------------------------------------------
template <typename OutT, bool BIAS, int MODE, int NJ>
__global__ __launch_bounds__(256, (NJ >= 3) ? 2 : 3) void gemm_bt(
    const unsigned short* __restrict__ A,
    const unsigned short* __restrict__ Bt,
    OutT* __restrict__ C,
    unsigned short* __restrict__ Vt,
    const float* __restrict__ bias,
    int Kd, int lda, int ldb, int ldc,
    long sA, long sB, long sC,
    float scale) {
  constexpr int BN    = NJ * 64;     // block N width
  constexpr int ROWS  = 128 + BN;    // staged rows per k-tile (A then B)
  constexpr int SLOTS = ROWS / 16;   // 1-KB staging slots (16 rows each)
  __shared__ unsigned short lds[2][ROWS * 32];

  const int bz = blockIdx.z;
  A  += (size_t)bz * sA + (size_t)blockIdx.x * 128 * lda;
  Bt += (size_t)bz * sB + (size_t)blockIdx.y * BN * ldb;

  const int tid  = threadIdx.x;
  const int wave = tid >> 6;
  const int lane = tid & 63;
  const int wm   = (wave >> 1) * 64;         // wave row offset
  const int wn   = (wave & 1) * (NJ * 32);   // wave col offset
  const int l32  = lane & 31;
  const int half = lane >> 5;
  // stage-side swizzle: this lane fetches global chunk cg/8 of its row
  const int cg   = ((lane & 3) ^ ((lane >> 2) & 3) ^ (lane >> 4)) * 8;
  // read-side: LDS chunk for global chunk (2h+half) at rows == l32 (mod 16)
  const int pswz = (l32 & 3) ^ ((l32 >> 2) & 3);

  auto stage = [&](int k0, int b) {
#pragma unroll
    for (int j = 0; j < SLOTS / 4; ++j) {
      const int s = wave + 4 * j;            // slot (wave-uniform)
      const int r = s * 16 + (lane >> 2);    // row in concat(A,B) space
      const unsigned short* src = (s < 8) ? (A + (size_t)r * lda)
                                          : (Bt + (size_t)(r - 128) * ldb);
      gload_lds16(src + k0 + cg, (char*)&lds[b][0] + s * 1024);
    }
  };

  f32x16 acc[2][NJ] = {};

  stage(0, 0);
  int cur = 0;
  for (int k0 = 0; k0 < Kd; k0 += 32) {
    __syncthreads();                         // drains prefetch of lds[cur]
    if (k0 + 32 < Kd) stage(k0 + 32, cur ^ 1);

    const unsigned short* base = &lds[cur][0];
    bf16x8 af[2][2], bfr[NJ][2];
#pragma unroll
    for (int t = 0; t < 2; ++t)
#pragma unroll
      for (int h = 0; h < 2; ++h) {
        const int p = ((2 * h + half) ^ pswz) * 8;
        af[t][h] = *(const bf16x8*)&base[(wm + t * 32 + l32) * 32 + p];
      }
#pragma unroll
    for (int u = 0; u < NJ; ++u)
#pragma unroll
      for (int h = 0; h < 2; ++h) {
        const int p = ((2 * h + half) ^ pswz) * 8;
        bfr[u][h] = *(const bf16x8*)&base[(128 + wn + u * 32 + l32) * 32 + p];
      }
#pragma unroll
    for (int t = 0; t < 2; ++t)
#pragma unroll
      for (int u = 0; u < NJ; ++u) {
        acc[t][u] = __builtin_amdgcn_mfma_f32_32x32x16_bf16(af[t][0], bfr[u][0], acc[t][u], 0, 0, 0);
        acc[t][u] = __builtin_amdgcn_mfma_f32_32x32x16_bf16(af[t][1], bfr[u][1], acc[t][u], 0, 0, 0);
      }
    cur ^= 1;
  }

  const int row0 = blockIdx.x * 128 + wm;
  const int colb = blockIdx.y * BN;

  if constexpr (MODE == 1) {
#pragma unroll
    for (int t = 0; t < 2; ++t) {
#pragma unroll
      for (int u = 0; u < NJ; ++u) {
        const int gcol  = colb + wn + u * 32;   // multiple of 32
        const int piece = gcol >> 10;
        const float bv  = BIAS ? bias[gcol + l32] : 0.0f;
        if (piece < 2) {
          OutT* dst = C + (size_t)piece * sC;
          const int col = (gcol & 1023) + l32;
#pragma unroll
          for (int r = 0; r < 16; ++r) {
            const int row = row0 + t * 32 + (r & 3) + 8 * (r >> 2) + 4 * half;
            dst[(size_t)row * ldc + col] = (OutT)f2bf(acc[t][u][r] * scale + bv);
          }
        } else {
          // V piece: write transposed Vt[b][d][2048]
          const int d = (gcol & 1023) + l32;
          const int b = row0 >> 11;
          const int sbase = (row0 & 2047) + t * 32 + 4 * half;
#pragma unroll
          for (int g = 0; g < 4; ++g) {
            const int s0 = sbase + 8 * g;
            us4 pk;
            pk.x = f2bf(acc[t][u][4 * g + 0] * scale + bv);
            pk.y = f2bf(acc[t][u][4 * g + 1] * scale + bv);
            pk.z = f2bf(acc[t][u][4 * g + 2] * scale + bv);
            pk.w = f2bf(acc[t][u][4 * g + 3] * scale + bv);
            *(us4*)&Vt[((size_t)b << 21) + (size_t)d * 2048 + s0] = pk;
          }
        }
      }
    }
  } else {
    C += (size_t)bz * sC;
    const int col0 = colb + wn;
#pragma unroll
    for (int t = 0; t < 2; ++t) {
#pragma unroll
      for (int u = 0; u < NJ; ++u) {
        const int col = col0 + u * 32 + l32;
        const float bv = BIAS ? bias[col0 + u * 32 + l32] : 0.0f;
#pragma unroll
        for (int r = 0; r < 16; ++r) {
          const int row = row0 + t * 32 + (r & 3) + 8 * (r >> 2) + 4 * half;
          const float v = acc[t][u][r] * scale + bv;
          if constexpr (sizeof(OutT) == 4)
            C[(size_t)row * ldc + col] = v;
          else
            C[(size_t)row * ldc + col] = (OutT)f2bf(v);
        }
      }
    }
  }
}

// fp32 -> bf16 flat convert (4 elems/thread)
__global__ void cvt_x(const float* __restrict__ in, unsigned short* __restrict__ out, int n4) {
  const int i = blockIdx.x * blockDim.x + threadIdx.x;
  if (i < n4) {
    const float4 v = ((const float4*)in)[i];
    uint2 o;
    o.x = (unsigned)f2bf(v.x) | ((unsigned)f2bf(v.y) << 16);
    o.y = (unsigned)f2bf(v.z) | ((unsigned)f2bf(v.w) << 16);
    ((uint2*)out)[i] = o;
  }
}

// All 4 weight matrices (1024x1024 fp32) -> bf16 transposed, one launch.
__global__ void cvtT_w4(const float* __restrict__ Wq, const float* __restrict__ Wk,
                        const float* __restrict__ Wv, const float* __restrict__ Wo,
                        unsigned short* __restrict__ Wqkvb, unsigned short* __restrict__ Wob) {
  __shared__ unsigned short tile[64][65];
  const int z = blockIdx.z;
  const float* in = (z == 0) ? Wq : (z == 1) ? Wk : (z == 2) ? Wv : Wo;
  unsigned short* out = (z == 3) ? Wob : Wqkvb + (size_t)z * 1024 * 1024;
  const int r0 = blockIdx.y * 64, c0 = blockIdx.x * 64;
  for (int i = threadIdx.y; i < 64; i += 4)
    tile[i][threadIdx.x] = f2bf(in[(size_t)(r0 + i) * 1024 + c0 + threadIdx.x]);
  __syncthreads();
  for (int i = threadIdx.y; i < 64; i += 4)
    out[(size_t)(c0 + i) * 1024 + r0 + threadIdx.x] = tile[threadIdx.x][i];
}

// concat bq|bk|bv into bqkv
__global__ void concat_bias(const float* __restrict__ bq, const float* __restrict__ bk,
                            const float* __restrict__ bv, float* __restrict__ dst) {
  const int z = blockIdx.x;
  const float* src = (z == 0) ? bq : (z == 1) ? bk : bv;
  const int i = threadIdx.x;
  ((float4*)(dst + z * 1024))[i] = ((const float4*)src)[i];
}

// One block per row of 2048 bf16 scores; softmax in fp32, bf16 in place.
__global__ __launch_bounds__(256) void softmax_bf16(unsigned short* __restrict__ scores) {
  unsigned short* p = scores + (size_t)blockIdx.x * 2048;
  const int t = threadIdx.x;
  uint4 raw = ((const uint4*)p)[t];
  float v[8];
  v[0] = __uint_as_float(raw.x << 16); v[1] = __uint_as_float(raw.x & 0xffff0000u);
  v[2] = __uint_as_float(raw.y << 16); v[3] = __uint_as_float(raw.y & 0xffff0000u);
  v[4] = __uint_as_float(raw.z << 16); v[5] = __uint_as_float(raw.z & 0xffff0000u);
  v[6] = __uint_as_float(raw.w << 16); v[7] = __uint_as_float(raw.w & 0xffff0000u);

  float m = v[0];
#pragma unroll
  for (int i = 1; i < 8; ++i) m = fmaxf(m, v[i]);
#pragma unroll
  for (int off = 32; off; off >>= 1) m = fmaxf(m, __shfl_xor(m, off, 64));

  __shared__ float red[4];
  __shared__ float bcast[2];
  const int wave = t >> 6, lane = t & 63;
  if (lane == 0) red[wave] = m;
  __syncthreads();
  if (t == 0) bcast[0] = fmaxf(fmaxf(red[0], red[1]), fmaxf(red[2], red[3]));
  __syncthreads();
  m = bcast[0];

  float s = 0.f;
#pragma unroll
  for (int i = 0; i < 8; ++i) { v[i] = __expf(v[i] - m); s += v[i]; }
#pragma unroll
  for (int off = 32; off; off >>= 1) s += __shfl_xor(s, off, 64);
  if (lane == 0) red[wave] = s;
  __syncthreads();
  if (t == 0) bcast[1] = red[0] + red[1] + red[2] + red[3];
  __syncthreads();
  const float inv = 1.0f / bcast[1];

  uint4 ov;
  ov.x = (unsigned)f2bf(v[0] * inv) | ((unsigned)f2bf(v[1] * inv) << 16);
  ov.y = (unsigned)f2bf(v[2] * inv) | ((unsigned)f2bf(v[3] * inv) << 16);
  ov.z = (unsigned)f2bf(v[4] * inv) | ((unsigned)f2bf(v[5] * inv) << 16);
  ov.w = (unsigned)f2bf(v[6] * inv) | ((unsigned)f2bf(v[7] * inv) << 16);
  ((uint4*)p)[t] = ov;
}

// ---------------------------------------------------------------------------
extern "C" void kernel_launch(void* const* d_in, const int* in_sizes, int n_in,
                              void* d_out, int out_size, void* d_ws, size_t ws_size,
                              hipStream_t stream) {
  const float* x  = (const float*)d_in[0];
  const float* Wq = (const float*)d_in[1];
  const float* bq = (const float*)d_in[2];
  const float* Wk = (const float*)d_in[3];
  const float* bk = (const float*)d_in[4];
  const float* Wv = (const float*)d_in[5];
  const float* bv = (const float*)d_in[6];
  const float* Wo = (const float*)d_in[7];
  const float* bo = (const float*)d_in[8];
  float* out = (float*)d_out;

  char* ws = (char*)d_ws;
  size_t off = 0;
  auto alloc = [&](size_t bytes) { char* p = ws + off; off += (bytes + 255) & ~255UL; return p; };
  unsigned short* xb    = (unsigned short*)alloc(8192UL * 1024 * 2);     // 16 MiB
  unsigned short* Wqkvb = (unsigned short*)alloc(3072UL * 1024 * 2);     // 6 MiB
  unsigned short* Wob   = (unsigned short*)alloc(1024UL * 1024 * 2);     // 2 MiB
  float*          bqkv  = (float*)alloc(3072UL * 4);
  unsigned short* Qb    = (unsigned short*)alloc(8192UL * 1024 * 2);     // 16 MiB (piece 0)
  unsigned short* Kb    = (unsigned short*)alloc(8192UL * 1024 * 2);     // 16 MiB (piece 1)
  unsigned short* Vtb   = (unsigned short*)alloc(4UL * 1024 * 2048 * 2); // 16 MiB [b][d][s]
  unsigned short* attn  = (unsigned short*)alloc(8192UL * 2048 * 2);     // 32 MiB bf16 scores
  unsigned short* ctxb  = (unsigned short*)alloc(8192UL * 1024 * 2);     // 16 MiB

  const dim3 blk(256);

  // input convert + all weight transposes + bias concat
  cvt_x<<<2097152 / 256, 256, 0, stream>>>(x, xb, 2097152);
  cvtT_w4<<<dim3(16, 16, 4), dim3(64, 4), 0, stream>>>(Wq, Wk, Wv, Wo, Wqkvb, Wob);
  concat_bias<<<3, 256, 0, stream>>>(bq, bk, bv, bqkv);

  // fused QKV projection (NJ=3: 128x192 tiles, grid 1024 = 2 even rounds),
  // Q,K compact + V written transposed to Vtb.
  gemm_bt<unsigned short, true, 1, 3><<<dim3(64, 16, 1), blk, 0, stream>>>(
      xb, Wqkvb, Qb, Vtb, bqkv, 1024, 1024, 1024, 1024, 0, 0, 8192L * 1024, 1.0f);

  // scores = (Q @ K^T) / 32 -> bf16, per batch (NJ=4, grid 512 = 1 round)
  gemm_bt<unsigned short, false, 0, 4><<<dim3(16, 8, 4), blk, 0, stream>>>(
      Qb, Kb, attn, nullptr, nullptr, 1024, 1024, 1024, 2048,
      2048L * 1024, 2048L * 1024, 2048L * 2048, 0.03125f);

  // softmax rows in place (bf16, dense ld=2048)
  softmax_bf16<<<8192, 256, 0, stream>>>(attn);

  // ctx = attn @ V  (attn lda=2048, Vt is Bt layout) (NJ=2)
  gemm_bt<unsigned short, false, 0, 2><<<dim3(16, 8, 4), blk, 0, stream>>>(
      attn, Vtb, ctxb, nullptr, nullptr, 2048, 2048, 2048, 1024,
      2048L * 2048, 1024L * 2048, 2048L * 1024, 1.0f);

  // out = ctx @ Wo + bo (fp32 out) (NJ=2)
  gemm_bt<float, true, 0, 2><<<dim3(64, 8, 1), blk, 0, stream>>>(
      ctxb, Wob, out, nullptr, bo, 1024, 1024, 1024, 1024, 0, 0, 0, 1.0f);
}